// Round 6
// baseline (100.425 us; speedup 1.0000x reference)
//
#include <hip/hip_runtime.h>
#include <math.h>

typedef float v2f __attribute__((ext_vector_type(2)));

namespace {
constexpr int L = 12, D = 64, E = 8;
constexpr long ROWS = 128L * 4096L;  // B*N
}

// One thread processes TWO rows, packed as float2 so fp-contract emits
// v_pk_fma_f32 (halves VALU time vs scalar fma; memory-bound after that).
// Weights are read with wave-uniform indices -> compiler scalarizes to
// s_load (K$), leaving VMEM for the x stream. No LDS needed.
__global__ __launch_bounds__(256) void gating_kernel(
    const float* __restrict__ x, const float* __restrict__ W1,
    const float* __restrict__ b1, const float* __restrict__ W2,
    const float* __restrict__ b2, float* __restrict__ out)
{
  const int gid = blockIdx.x * blockDim.x + threadIdx.x;   // row-pair id
  const size_t base = (size_t)gid * 2;                     // first row

  // Load 2 rows of x: 24 contiguous floats = 6 x float4 (96B, 16B aligned)
  float xr[2 * L];
  const float4* xp = reinterpret_cast<const float4*>(x + base * L);
#pragma unroll
  for (int i = 0; i < 6; ++i) {
    float4 v = xp[i];
    xr[4 * i + 0] = v.x; xr[4 * i + 1] = v.y;
    xr[4 * i + 2] = v.z; xr[4 * i + 3] = v.w;
  }
  v2f xv[L];
#pragma unroll
  for (int l = 0; l < L; ++l) xv[l] = (v2f){xr[l], xr[L + l]};

  v2f lg[E];
#pragma unroll
  for (int e = 0; e < E; ++e) { float b = b2[e]; lg[e] = (v2f){b, b}; }

  // d blocked by 8: W2 rows become contiguous s_load_dwordx8 candidates,
  // h-chunk stays in 16 VGPRs. Accumulation order matches reference
  // (l ascending for h, d ascending for logits).
  for (int dc = 0; dc < D; dc += 8) {
    v2f h[8];
#pragma unroll
    for (int j = 0; j < 8; ++j) { float b = b1[dc + j]; h[j] = (v2f){b, b}; }
#pragma unroll
    for (int l = 0; l < L; ++l) {
      v2f xl = xv[l];
#pragma unroll
      for (int j = 0; j < 8; ++j) {
        float w = W1[l * D + dc + j];      // wave-uniform -> s_load
        h[j] += xl * (v2f){w, w};          // contracts to v_pk_fma_f32
      }
    }
#pragma unroll
    for (int j = 0; j < 8; ++j) {
      v2f hj = h[j];
      hj.x = fmaxf(hj.x, 0.0f);
      hj.y = fmaxf(hj.y, 0.0f);
#pragma unroll
      for (int e = 0; e < E; ++e) {
        float w = W2[(dc + j) * E + e];    // contiguous 8 -> s_load_dwordx8
        lg[e] += hj * (v2f){w, w};
      }
    }
  }

  // Epilogue per row: top-2 (ties -> lowest index, matching jax.lax.top_k),
  // softmax over the 2 selected logits, scatter into 8 outputs.
  float o[2][E];
#pragma unroll
  for (int c = 0; c < 2; ++c) {
    float v[E];
#pragma unroll
    for (int e = 0; e < E; ++e) v[e] = (c == 0) ? lg[e].x : lg[e].y;
    int i1 = 0; float m1 = v[0];
#pragma unroll
    for (int e = 1; e < E; ++e) { if (v[e] > m1) { m1 = v[e]; i1 = e; } }
    int i2 = 0; float m2 = -INFINITY;
#pragma unroll
    for (int e = 0; e < E; ++e) { if (e != i1 && v[e] > m2) { m2 = v[e]; i2 = e; } }
    float t = expf(m2 - m1);           // softmax with max subtracted
    float inv = 1.0f / (1.0f + t);
    float g1 = inv, g2 = t * inv;
#pragma unroll
    for (int e = 0; e < E; ++e)
      o[c][e] = (e == i1) ? g1 : ((e == i2) ? g2 : 0.0f);
  }

  // 2 rows * 8 floats = 64B contiguous -> 4 x float4 stores
  float4* op = reinterpret_cast<float4*>(out + base * E);
#pragma unroll
  for (int i = 0; i < 4; ++i) {
    op[i] = make_float4(o[i >> 1][(i & 1) * 4 + 0], o[i >> 1][(i & 1) * 4 + 1],
                        o[i >> 1][(i & 1) * 4 + 2], o[i >> 1][(i & 1) * 4 + 3]);
  }
}

extern "C" void kernel_launch(void* const* d_in, const int* in_sizes, int n_in,
                              void* d_out, int out_size, void* d_ws, size_t ws_size,
                              hipStream_t stream) {
  const float* x  = (const float*)d_in[0];
  const float* W1 = (const float*)d_in[1];
  const float* b1 = (const float*)d_in[2];
  const float* W2 = (const float*)d_in[3];
  const float* b2 = (const float*)d_in[4];
  float* out = (float*)d_out;

  const int threads = 256;
  const long pairs = ROWS / 2;                       // 262144 row-pairs
  const int blocks = (int)((pairs + threads - 1) / threads);  // 1024 blocks
  gating_kernel<<<blocks, threads, 0, stream>>>(x, W1, b1, W2, b2, out);
}